// Round 6
// baseline (801.822 us; speedup 1.0000x reference)
//
#include <hip/hip_runtime.h>
#include <hip/hip_bf16.h>
#include <cfloat>

#define BATCH 4
#define DIMC 1792
#define HWSZ 3136
#define NPROT 3136
#define NPAD 3200           // NPROT padded to a multiple of 128
#define MROWS 12544
#define NPT2 25             // NPAD/128 column tiles in gemm2

typedef unsigned short u16;
typedef unsigned int u32;
using bf16x8 = __attribute__((ext_vector_type(8))) short;
using f32x4  = __attribute__((ext_vector_type(4))) float;

__device__ __forceinline__ float bf2f(u32 u) { return __uint_as_float(u << 16); }
__device__ __forceinline__ u16 f2bf(float x) {
    __hip_bfloat16 h = __float2bfloat16(x);   // RNE
    return *reinterpret_cast<u16*>(&h);
}

// async global->LDS, 16B per lane; LDS dest = wave-uniform base + lane*16
__device__ __forceinline__ void gload_lds16(const u16* g, u16* l) {
    __builtin_amdgcn_global_load_lds(
        (const __attribute__((address_space(1))) void*)g,
        (__attribute__((address_space(3))) void*)l, 16, 0, 0);
}

__device__ __forceinline__ void ins3(float v, float& t0, float& t1, float& t2) {
    if (v < t2) {
        if (v < t1) {
            t2 = t1;
            if (v < t0) { t1 = t0; t0 = v; }
            else        { t1 = v; }
        } else {
            t2 = v;
        }
    }
}

// bijective XCD chunking (m204): consecutive swz ids land on one XCD
__device__ __forceinline__ int xcd_swz(int bid, int nwg) {
    int q = nwg >> 3, r = nwg & 7;
    int xcd = bid & 7, idx = bid >> 3;
    return (xcd < r ? xcd * (q + 1) : r * (q + 1) + (xcd - r) * q) + idx;
}

// ---- pack p[b][c][hw] (fp32) -> Pbf[r=b*HWSZ+hw][c] (bf16) ----------------
__global__ void pack_p_kernel(const float* __restrict__ p, u16* __restrict__ Pbf) {
    __shared__ float tile[32][33];      // [c_local][hw_local]
    int hw0 = blockIdx.x * 32, c0 = blockIdx.y * 32, b = blockIdx.z;
    int tid = threadIdx.x;
    int tx = tid & 31, ty = tid >> 5;   // load: tx=hw, ty+j = c
#pragma unroll
    for (int j = 0; j < 32; j += 8)
        tile[ty + j][tx] = p[((size_t)(b * DIMC + c0 + ty + j)) * HWSZ + hw0 + tx];
    __syncthreads();
    int hwl = tid >> 3;                 // 0..31
    int c4  = (tid & 7) * 4;            // 0..28
    int r = b * HWSZ + hw0 + hwl;
    ushort4 o;
    o.x = f2bf(tile[c4 + 0][hwl]);
    o.y = f2bf(tile[c4 + 1][hwl]);
    o.z = f2bf(tile[c4 + 2][hwl]);
    o.w = f2bf(tile[c4 + 3][hwl]);
    *(ushort4*)(Pbf + (size_t)r * DIMC + c0 + c4) = o;
}

// ---- cast W[d][c] fp32 -> Wbf[d][c] bf16 ----------------------------------
__global__ void pack_w_kernel(const float* __restrict__ W, u16* __restrict__ Wbf) {
    size_t i = (size_t)(blockIdx.x * 256 + threadIdx.x) * 4;   // exact grid
    float4 v = *(const float4*)(W + i);
    ushort4 o;
    o.x = f2bf(v.x); o.y = f2bf(v.y); o.z = f2bf(v.z); o.w = f2bf(v.w);
    *(ushort4*)(Wbf + i) = o;
}

// ---- pack C[d][j] fp32 -> CTbf[j][d] bf16, fused cn[j] += sum_d C^2 -------
__global__ void pack_c_kernel(const float* __restrict__ C, u16* __restrict__ CTbf,
                              float* __restrict__ cn) {
    __shared__ float tile[32][33];      // [d_local][j_local]
    int j0 = blockIdx.x * 32, d0 = blockIdx.y * 32;
    int tid = threadIdx.x;
    int tx = tid & 31, ty = tid >> 5;
#pragma unroll
    for (int jj = 0; jj < 32; jj += 8)
        tile[ty + jj][tx] = C[(size_t)(d0 + ty + jj) * NPROT + j0 + tx];
    __syncthreads();
    int jl = tid >> 3;                  // 0..31
    int d4 = (tid & 7) * 4;
    float s = 0.f;
    ushort4 o;
    {
        float f0 = tile[d4 + 0][jl], f1 = tile[d4 + 1][jl];
        float f2 = tile[d4 + 2][jl], f3 = tile[d4 + 3][jl];
        o.x = f2bf(f0); o.y = f2bf(f1); o.z = f2bf(f2); o.w = f2bf(f3);
        s = f0 * f0 + f1 * f1 + f2 * f2 + f3 * f3;   // fp32, pre-rounding
    }
    *(ushort4*)(CTbf + (size_t)(j0 + jl) * DIMC + d0 + d4) = o;
    // threads with same jl are 8 consecutive lanes -> butterfly then 1 atomic
#pragma unroll
    for (int off = 1; off < 8; off <<= 1) s += __shfl_xor(s, off);
    if ((tid & 7) == 0) atomicAdd(&cn[j0 + jl], s);
}

// ---- GEMM1: phibf[r][n] = sum_k Pbf[r][k]*Wbf[n][k] + bias[n]; rn fused ---
// m97 structure: 128x128 tile, 4 waves, BK=32, global_load_lds width-16.
__global__ __launch_bounds__(256) void gemm_bias_kernel(
    const u16* __restrict__ A, const u16* __restrict__ B,
    const float* __restrict__ bias, u16* __restrict__ out, int ldo, int nby,
    float* __restrict__ rn)
{
    __shared__ __align__(16) u16 Als[128 * 32];
    __shared__ __align__(16) u16 Bls[128 * 32];
    const int tid  = threadIdx.x;
    const int wid  = tid >> 6;
    const int lane = tid & 63;
    const int swz = xcd_swz(blockIdx.x, gridDim.x);
    const int r0 = (swz / nby) * 128;
    const int n0 = (swz % nby) * 128;

    const int srow = lane >> 2;
    const int sseg = (lane & 3) * 8;
    const u16* Ag = A + (size_t)(r0 + wid * 32 + srow) * DIMC + sseg;
    const u16* Bg = B + (size_t)(n0 + wid * 32 + srow) * DIMC + sseg;
    u16* AlsW = Als + wid * 1024;
    u16* BlsW = Bls + wid * 1024;

    const int wm = (wid >> 1) * 64;
    const int wn = (wid & 1) * 64;
    const int lrow = lane & 15;
    const int kseg = (lane >> 4) * 8;
    const int rsub = (lane >> 4) * 4;

    f32x4 acc[4][4];
#pragma unroll
    for (int m = 0; m < 4; ++m)
#pragma unroll
        for (int n = 0; n < 4; ++n)
            acc[m][n] = (f32x4){0.f, 0.f, 0.f, 0.f};

    for (int k0 = 0; k0 < DIMC; k0 += 32) {
        gload_lds16(Ag + k0,                      AlsW);
        gload_lds16(Ag + (size_t)16 * DIMC + k0,  AlsW + 512);
        gload_lds16(Bg + k0,                      BlsW);
        gload_lds16(Bg + (size_t)16 * DIMC + k0,  BlsW + 512);
        __syncthreads();
        bf16x8 af[4], bv[4];
#pragma unroll
        for (int m = 0; m < 4; ++m)
            af[m] = *(const bf16x8*)(Als + (wm + m * 16 + lrow) * 32 + kseg);
#pragma unroll
        for (int n = 0; n < 4; ++n)
            bv[n] = *(const bf16x8*)(Bls + (wn + n * 16 + lrow) * 32 + kseg);
#pragma unroll
        for (int m = 0; m < 4; ++m)
#pragma unroll
            for (int n = 0; n < 4; ++n)
                acc[m][n] = __builtin_amdgcn_mfma_f32_16x16x32_bf16(
                    af[m], bv[n], acc[m][n], 0, 0, 0);
        __syncthreads();
    }

    // epilogue: bias add, bf16 store, fused rn += sum(phi^2)
    float bsv[4];
#pragma unroll
    for (int n = 0; n < 4; ++n) bsv[n] = bias[n0 + wn + n * 16 + lrow];
#pragma unroll
    for (int m = 0; m < 4; ++m) {
        float rsum[4] = {0.f, 0.f, 0.f, 0.f};
#pragma unroll
        for (int n = 0; n < 4; ++n) {
            int col = n0 + wn + n * 16 + lrow;
            f32x4 v = acc[m][n];
#pragma unroll
            for (int i = 0; i < 4; ++i) {
                float f = v[i] + bsv[n];
                rsum[i] += f * f;
                int row = r0 + wm + m * 16 + rsub + i;
                out[(size_t)row * ldo + col] = f2bf(f);
            }
        }
#pragma unroll
        for (int i = 0; i < 4; ++i) {
            float s = rsum[i];
#pragma unroll
            for (int off = 1; off < 16; off <<= 1) s += __shfl_xor(s, off);
            if (lrow == 0)
                atomicAdd(&rn[r0 + wm + m * 16 + rsub + i], s);
        }
    }
}

// ---- GEMM2 + fused top-3: ptop[row][pt][3] partial mins -------------------
// t[row][col] = cn[col] - 2 * sum_k phibf[row][k]*CTbf[col][k]
__global__ __launch_bounds__(256) void gemm_top3_kernel(
    const u16* __restrict__ A, const u16* __restrict__ B,
    const float* __restrict__ cn, float* __restrict__ ptop)
{
    __shared__ __align__(16) u16 Als[128 * 32];
    __shared__ __align__(16) u16 Bls[128 * 32];
    __shared__ float red[128][2][3];
    const int tid  = threadIdx.x;
    const int wid  = tid >> 6;
    const int lane = tid & 63;
    const int swz = xcd_swz(blockIdx.x, gridDim.x);
    const int r0 = (swz / NPT2) * 128;
    const int pt = swz % NPT2;
    const int n0 = pt * 128;

    const int srow = lane >> 2;
    const int sseg = (lane & 3) * 8;
    const u16* Ag = A + (size_t)(r0 + wid * 32 + srow) * DIMC + sseg;
    const u16* Bg = B + (size_t)(n0 + wid * 32 + srow) * DIMC + sseg;
    u16* AlsW = Als + wid * 1024;
    u16* BlsW = Bls + wid * 1024;

    const int wm = (wid >> 1) * 64;
    const int wn = (wid & 1) * 64;
    const int lrow = lane & 15;
    const int kseg = (lane >> 4) * 8;
    const int rsub = (lane >> 4) * 4;

    f32x4 acc[4][4];
#pragma unroll
    for (int m = 0; m < 4; ++m)
#pragma unroll
        for (int n = 0; n < 4; ++n)
            acc[m][n] = (f32x4){0.f, 0.f, 0.f, 0.f};

    for (int k0 = 0; k0 < DIMC; k0 += 32) {
        gload_lds16(Ag + k0,                      AlsW);
        gload_lds16(Ag + (size_t)16 * DIMC + k0,  AlsW + 512);
        gload_lds16(Bg + k0,                      BlsW);
        gload_lds16(Bg + (size_t)16 * DIMC + k0,  BlsW + 512);
        __syncthreads();
        bf16x8 af[4], bv[4];
#pragma unroll
        for (int m = 0; m < 4; ++m)
            af[m] = *(const bf16x8*)(Als + (wm + m * 16 + lrow) * 32 + kseg);
#pragma unroll
        for (int n = 0; n < 4; ++n)
            bv[n] = *(const bf16x8*)(Bls + (wn + n * 16 + lrow) * 32 + kseg);
#pragma unroll
        for (int m = 0; m < 4; ++m)
#pragma unroll
            for (int n = 0; n < 4; ++n)
                acc[m][n] = __builtin_amdgcn_mfma_f32_16x16x32_bf16(
                    af[m], bv[n], acc[m][n], 0, 0, 0);
        __syncthreads();
    }

    // fused epilogue: per-lane 4-col top3 per row, 16-lane-group shfl merge,
    // cross-wave merge via 3KB LDS, block-partial -> ptop[row][pt][3].
    float cnv[4];
#pragma unroll
    for (int n = 0; n < 4; ++n) {
        int col = n0 + wn + n * 16 + lrow;
        cnv[n] = (col < NPROT) ? cn[col] : FLT_MAX;   // padded cols never win
    }
#pragma unroll
    for (int m = 0; m < 4; ++m) {
#pragma unroll
        for (int i = 0; i < 4; ++i) {
            float t0 = FLT_MAX, t1 = FLT_MAX, t2 = FLT_MAX;
#pragma unroll
            for (int n = 0; n < 4; ++n)
                ins3(cnv[n] - 2.f * acc[m][n][i], t0, t1, t2);
#pragma unroll
            for (int off = 1; off < 16; off <<= 1) {
                float s0 = __shfl_xor(t0, off);
                float s1 = __shfl_xor(t1, off);
                float s2 = __shfl_xor(t2, off);
                ins3(s0, t0, t1, t2);
                ins3(s1, t0, t1, t2);
                ins3(s2, t0, t1, t2);
            }
            if (lrow == 0) {
                int row = wm + m * 16 + rsub + i;      // 0..127 in block
                red[row][wid & 1][0] = t0;
                red[row][wid & 1][1] = t1;
                red[row][wid & 1][2] = t2;
            }
        }
    }
    __syncthreads();
    if (tid < 128) {
        float t0 = red[tid][0][0], t1 = red[tid][0][1], t2 = red[tid][0][2];
        ins3(red[tid][1][0], t0, t1, t2);
        ins3(red[tid][1][1], t0, t1, t2);
        ins3(red[tid][1][2], t0, t1, t2);
        size_t base = ((size_t)(r0 + tid) * NPT2 + pt) * 3;
        ptop[base + 0] = t0;
        ptop[base + 1] = t1;
        ptop[base + 2] = t2;
    }
}

// ---- final: merge 25x3 partials + sqrt + softmin --------------------------
__global__ void final_kernel(const float* __restrict__ ptop,
                             const float* __restrict__ rn,
                             float* __restrict__ out) {
    int r = blockIdx.x * 256 + threadIdx.x;   // exact: MROWS/256 = 49
    float t0 = FLT_MAX, t1 = FLT_MAX, t2 = FLT_MAX;
    const float* pp = ptop + (size_t)r * NPT2 * 3;
    for (int q = 0; q < NPT2 * 3; ++q) ins3(pp[q], t0, t1, t2);
    float rv = rn[r];
    float d0 = sqrtf(rv + t0), d1 = sqrtf(rv + t1), d2 = sqrtf(rv + t2);
    float w0 = 1.f / (1.f + expf(d0 - d1) + expf(d0 - d2));
    out[r] = w0 * d0;
}

extern "C" void kernel_launch(void* const* d_in, const int* in_sizes, int n_in,
                              void* d_out, int out_size, void* d_ws, size_t ws_size,
                              hipStream_t stream) {
    const float* p    = (const float*)d_in[0];
    const float* W    = (const float*)d_in[1];
    const float* bias = (const float*)d_in[2];
    const float* C    = (const float*)d_in[3];
    float* out = (float*)d_out;

    char* w = (char*)d_ws;
    u16* Pbf   = (u16*)w;  w += (size_t)MROWS * DIMC * 2;   // 45.0 MB
    u16* Wbf   = (u16*)w;  w += (size_t)DIMC * DIMC * 2;    //  6.4 MB
    u16* CTbf  = (u16*)w;  w += (size_t)NPAD * DIMC * 2;    // 11.5 MB
    u16* phibf = (u16*)w;  w += (size_t)MROWS * DIMC * 2;   // 45.0 MB
    float* ptop = (float*)w; w += (size_t)MROWS * NPT2 * 3 * 4;  // 3.8 MB
    float* cn  = (float*)w; w += (size_t)NPROT * 4;
    float* rn  = (float*)w;                                  // total ~112 MB

    // zero the atomic accumulators (cn and rn are adjacent)
    hipMemsetAsync(cn, 0, (NPROT + MROWS) * sizeof(float), stream);

    pack_p_kernel<<<dim3(HWSZ / 32, DIMC / 32, BATCH), 256, 0, stream>>>(p, Pbf);
    pack_w_kernel<<<(DIMC * DIMC / 4) / 256, 256, 0, stream>>>(W, Wbf);
    pack_c_kernel<<<dim3(NPROT / 32, DIMC / 32), 256, 0, stream>>>(C, CTbf, cn);

    gemm_bias_kernel<<<(MROWS / 128) * (DIMC / 128), 256, 0, stream>>>(
        Pbf, Wbf, bias, phibf, DIMC, DIMC / 128, rn);
    gemm_top3_kernel<<<(MROWS / 128) * NPT2, 256, 0, stream>>>(
        phibf, CTbf, cn, ptop);
    final_kernel<<<MROWS / 256, 256, 0, stream>>>(ptop, rn, out);
}